// Round 1
// baseline (9249.274 us; speedup 1.0000x reference)
//
#include <hip/hip_runtime.h>
#include <hip/hip_bf16.h>

// GRU-variant: B=64, T=512, D=L=1024.
// Phase 1: P[b*T+t][3j+s] = x-part preactivations, triplet-permuted cols:
//   s=0: x@w_W[:, j] + w_b[j]        (hidden gate x-part)
//   s=1: x@w_W[:, 1024+j] + w_b[1024+j] (output gate x-part)
//   s=2: x@wx_W[:, j] + wx_b[j]      (qx)
// Phase 2 (per step t): G = h_bf16 @ RT^T (triplet-permuted recurrent weights),
//   fused epilogue computes h_new, writes d_out row t and next bf16 h.

typedef __attribute__((ext_vector_type(4))) int   int4v;
typedef __attribute__((ext_vector_type(4))) short short4v;
typedef __attribute__((ext_vector_type(8))) short bf16x8;
typedef __attribute__((ext_vector_type(4))) float f32x4;

union Pack16 { int4v i; short4v s[2]; };
union FragU  { bf16x8 v; short4v s[2]; };

__device__ __forceinline__ short f2bf(float f) {
  union { float f; unsigned u; } v; v.f = f;
  unsigned r = v.u + 0x7fffu + ((v.u >> 16) & 1u);   // round-to-nearest-even
  return (short)(r >> 16);
}
__device__ __forceinline__ float bf2f(short s) {
  union { unsigned u; float f; } v; v.u = ((unsigned)(unsigned short)s) << 16;
  return v.f;
}

// ---------------- prep kernels ----------------

__global__ __launch_bounds__(256) void cast_x_kernel(const float* __restrict__ xf,
                                                     short* __restrict__ xbf, int n4) {
  int i = blockIdx.x * 256 + threadIdx.x;
  if (i < n4) {
    float4 v = ((const float4*)xf)[i];
    short4v o;
    o.x = f2bf(v.x); o.y = f2bf(v.y); o.z = f2bf(v.z); o.w = f2bf(v.w);
    ((short4v*)xbf)[i] = o;
  }
}

// XwT: [3072][1024] bf16, row n=3j+s gathers column col(n) of the x-part weights.
// RT : [3104][1024] bf16 (rows 3072..3103 zero pad), h-part weights.
__global__ __launch_bounds__(256) void prep_weights(const float* __restrict__ wW,
                                                    const float* __restrict__ wxW,
                                                    const float* __restrict__ whW,
                                                    short* __restrict__ XwT,
                                                    short* __restrict__ RT) {
  int nb = blockIdx.x;
  if (nb < 3072) {
    int n = nb, j = n / 3, s = n % 3;
    for (int k = threadIdx.x; k < 1024; k += 256) {
      float v = (s == 0) ? wW[k * 2048 + j]
              : (s == 1) ? wW[k * 2048 + 1024 + j]
                         : wxW[k * 1024 + j];
      XwT[n * 1024 + k] = f2bf(v);
    }
  } else {
    int n = nb - 3072;  // 0..3103
    for (int k = threadIdx.x; k < 1024; k += 256) {
      float v = 0.f;
      if (n < 3072) {
        int j = n / 3, s = n % 3;
        v = (s == 0) ? wW[(1024 + k) * 2048 + j]
          : (s == 1) ? wW[(1024 + k) * 2048 + 1024 + j]
                     : whW[k * 1024 + j];
      }
      RT[n * 1024 + k] = f2bf(v);
    }
  }
}

// biasP (fp32, permuted) + h0 -> bf16 buffer 0
__global__ __launch_bounds__(256) void prep_misc(const float* __restrict__ wb,
                                                 const float* __restrict__ wxb,
                                                 const float* __restrict__ h0,
                                                 float* __restrict__ biasP,
                                                 short* __restrict__ hbf0) {
  int i = blockIdx.x * 256 + threadIdx.x;
  if (i < 65536) {
    hbf0[i] = f2bf(h0[i]);
  } else {
    int n = i - 65536;
    if (n < 3072) {
      int j = n / 3, s = n % 3;
      biasP[n] = (s == 0) ? wb[j] : (s == 1) ? wb[1024 + j] : wxb[j];
    }
  }
}

// ---------------- phase 1: P-GEMM ----------------
// C[32768x3072] = A[32768x1024](bf16) @ B[1024x3072] + biasP, B stored transposed
// as Bt[3072][1024]. 128x128 tile, BK=32, 4 waves (2x2), 16x16x32 MFMA,
// LDS rows padded to 36 shorts (72 B): ds b64-aligned, <=2-way bank aliasing.
__global__ __launch_bounds__(256) void pgemm_kernel(const short* __restrict__ A,
                                                    const short* __restrict__ Bt,
                                                    const float* __restrict__ biasP,
                                                    short* __restrict__ P) {
  __shared__ short As[128][36];
  __shared__ short Bs[128][36];
  const int tid = threadIdx.x;
  const int m0 = blockIdx.y << 7;
  const int n0 = blockIdx.x << 7;
  const int w = tid >> 6, lane = tid & 63;
  const int wm = w >> 1, wn = w & 1;
  const int q = lane >> 4, r = lane & 15;
  const int srow = tid >> 1, shalf = tid & 1;

  const f32x4 zero = {0.f, 0.f, 0.f, 0.f};
  f32x4 acc[4][4];
#pragma unroll
  for (int a = 0; a < 4; ++a)
#pragma unroll
    for (int b = 0; b < 4; ++b) acc[a][b] = zero;

  const short* gA = A + (long)(m0 + srow) * 1024 + shalf * 16;
  const short* gB = Bt + (long)(n0 + srow) * 1024 + shalf * 16;

  for (int kk = 0; kk < 1024; kk += 32) {
    Pack16 a0, a1, b0, b1;
    a0.i = *(const int4v*)(gA + kk);
    a1.i = *(const int4v*)(gA + kk + 8);
    b0.i = *(const int4v*)(gB + kk);
    b1.i = *(const int4v*)(gB + kk + 8);
    short* wA = &As[srow][shalf * 16];
    *(short4v*)(wA)      = a0.s[0];
    *(short4v*)(wA + 4)  = a0.s[1];
    *(short4v*)(wA + 8)  = a1.s[0];
    *(short4v*)(wA + 12) = a1.s[1];
    short* wB = &Bs[srow][shalf * 16];
    *(short4v*)(wB)      = b0.s[0];
    *(short4v*)(wB + 4)  = b0.s[1];
    *(short4v*)(wB + 8)  = b1.s[0];
    *(short4v*)(wB + 12) = b1.s[1];
    __syncthreads();

    FragU af[4], bfv[4];
#pragma unroll
    for (int mi = 0; mi < 4; ++mi) {
      const short* pa = &As[wm * 64 + mi * 16 + r][q * 8];
      af[mi].s[0] = *(const short4v*)pa;
      af[mi].s[1] = *(const short4v*)(pa + 4);
    }
#pragma unroll
    for (int ni = 0; ni < 4; ++ni) {
      const short* pb = &Bs[wn * 64 + ni * 16 + r][q * 8];
      bfv[ni].s[0] = *(const short4v*)pb;
      bfv[ni].s[1] = *(const short4v*)(pb + 4);
    }
#pragma unroll
    for (int mi = 0; mi < 4; ++mi)
#pragma unroll
      for (int ni = 0; ni < 4; ++ni)
        acc[mi][ni] = __builtin_amdgcn_mfma_f32_16x16x32_bf16(af[mi].v, bfv[ni].v,
                                                              acc[mi][ni], 0, 0, 0);
    __syncthreads();
  }

#pragma unroll
  for (int ni = 0; ni < 4; ++ni) {
    int gn = n0 + wn * 64 + ni * 16 + r;        // C/D: col = lane&15
    float bias = biasP[gn];
#pragma unroll
    for (int mi = 0; mi < 4; ++mi) {
      int gm = m0 + wm * 64 + mi * 16 + q * 4;  // row = quad*4 + reg
#pragma unroll
      for (int i = 0; i < 4; ++i)
        P[(long)(gm + i) * 3072 + gn] = f2bf(acc[mi][ni][i] + bias);
    }
  }
}

// ---------------- phase 2: one launch per timestep ----------------
// Block bb owns j in [8*bb, 8*bb+8): permuted cols n in [24*bb, 24*bb+24), padded
// to N=32 for MFMA. G[64x32] = h_bf16[64x1024] @ RT_slice^T, then fused epilogue.
__global__ __launch_bounds__(256) void step_kernel(const short* __restrict__ hA,
                                                   short* __restrict__ hB,
                                                   const short* __restrict__ RT,
                                                   const short* __restrict__ P,
                                                   const float* __restrict__ whb,
                                                   const float* __restrict__ hprev,
                                                   long hstride,
                                                   float* __restrict__ out,
                                                   int step) {
  __shared__ short As[64][36];
  __shared__ short Bs[32][36];
  __shared__ float Ld[64][25];
  const int bb = blockIdx.x;   // 0..127
  const int tid = threadIdx.x;
  const int w = tid >> 6, lane = tid & 63;
  const int q = lane >> 4, r = lane & 15;
  const int nt = w & 1, mt0 = (w >> 1) * 2;
  const int srow = tid >> 2, sc = tid & 3;

  const f32x4 zero = {0.f, 0.f, 0.f, 0.f};
  f32x4 acc0 = zero, acc1 = zero;

  const short* gA = hA + srow * 1024 + sc * 8;
  const short* gB = RT + (long)(bb * 24 + srow) * 1024 + sc * 8;  // deref only tid<128

  for (int kk = 0; kk < 1024; kk += 32) {
    Pack16 pa; pa.i = *(const int4v*)(gA + kk);
    short* wAp = &As[srow][sc * 8];
    *(short4v*)(wAp)     = pa.s[0];
    *(short4v*)(wAp + 4) = pa.s[1];
    if (tid < 128) {
      Pack16 pb; pb.i = *(const int4v*)(gB + kk);
      short* wBp = &Bs[srow][sc * 8];
      *(short4v*)(wBp)     = pb.s[0];
      *(short4v*)(wBp + 4) = pb.s[1];
    }
    __syncthreads();

    FragU bfrag, a0, a1;
    const short* pb = &Bs[nt * 16 + r][q * 8];
    bfrag.s[0] = *(const short4v*)pb;
    bfrag.s[1] = *(const short4v*)(pb + 4);
    const short* pa0 = &As[mt0 * 16 + r][q * 8];
    a0.s[0] = *(const short4v*)pa0;
    a0.s[1] = *(const short4v*)(pa0 + 4);
    const short* pa1 = &As[(mt0 + 1) * 16 + r][q * 8];
    a1.s[0] = *(const short4v*)pa1;
    a1.s[1] = *(const short4v*)(pa1 + 4);
    acc0 = __builtin_amdgcn_mfma_f32_16x16x32_bf16(a0.v, bfrag.v, acc0, 0, 0, 0);
    acc1 = __builtin_amdgcn_mfma_f32_16x16x32_bf16(a1.v, bfrag.v, acc1, 0, 0, 0);
    __syncthreads();
  }

  int nl = nt * 16 + r;
  if (nl < 24) {
#pragma unroll
    for (int i = 0; i < 4; ++i) {
      Ld[mt0 * 16 + q * 4 + i][nl]       = acc0[i];
      Ld[(mt0 + 1) * 16 + q * 4 + i][nl] = acc1[i];
    }
  }
  __syncthreads();

  for (int p = tid; p < 512; p += 256) {
    int b = p >> 3, jl = p & 7;
    int jg = (bb << 3) + jl;
    const short* prow = P + (long)(b * 512 + step) * 3072 + bb * 24 + jl * 3;
    float pg0 = bf2f(prow[0]);
    float pg1 = bf2f(prow[1]);
    float pq  = bf2f(prow[2]);
    float g0 = Ld[b][jl * 3 + 0];
    float g1 = Ld[b][jl * 3 + 1];
    float g2 = Ld[b][jl * 3 + 2];
    float gh = 1.f / (1.f + expf(-(pg0 + g0)));
    float go = 1.f / (1.f + expf(-(pg1 + g1)));
    float mem = pq + gh * (g2 + whb[jg]);
    float hp = hprev[(long)b * hstride + jg];
    float hn = go * hp + (1.f - go) * tanhf(mem);
    out[(long)(b * 512 + step) * 1024 + jg] = hn;
    hB[b * 1024 + jg] = f2bf(hn);
  }
}

// ---------------- launch ----------------

extern "C" void kernel_launch(void* const* d_in, const int* in_sizes, int n_in,
                              void* d_out, int out_size, void* d_ws, size_t ws_size,
                              hipStream_t stream) {
  const float* x   = (const float*)d_in[0];  // [64][512][1024]
  const float* h0  = (const float*)d_in[1];  // [64][1024]
  const float* wW  = (const float*)d_in[2];  // [2048][2048]
  const float* wb  = (const float*)d_in[3];  // [2048]
  const float* wxW = (const float*)d_in[4];  // [1024][1024]
  const float* wxb = (const float*)d_in[5];  // [1024]
  const float* whW = (const float*)d_in[6];  // [1024][1024]
  const float* whb = (const float*)d_in[7];  // [1024]
  float* out = (float*)d_out;                // [64][512][1024]

  // workspace layout (~268.3 MB total, all 16B-aligned)
  char* ws = (char*)d_ws;
  short* P     = (short*)(ws);                    // 32768*3072*2 = 201326592
  short* xbf   = (short*)(ws + 201326592);        // 33554432*2   =  67108864
  short* XwT   = (short*)(ws + 268435456);        // 3072*1024*2  =   6291456
  short* RT    = (short*)(ws + 274726912);        // 3104*1024*2  =   6356992
  float* biasP = (float*)(ws + 281083904);        // 3072*4
  short* hbf   = (short*)(ws + 281096192);        // 2*64*1024*2

  cast_x_kernel<<<dim3(32768), dim3(256), 0, stream>>>(x, xbf, 8388608);
  prep_weights<<<dim3(6176), dim3(256), 0, stream>>>(wW, wxW, whW, XwT, RT);
  prep_misc<<<dim3(268), dim3(256), 0, stream>>>(wb, wxb, h0, biasP, hbf);
  pgemm_kernel<<<dim3(24, 256), dim3(256), 0, stream>>>(xbf, XwT, biasP, P);

  for (int t = 0; t < 512; ++t) {
    const short* hA = hbf + (t & 1) * 65536;
    short* hB       = hbf + ((t + 1) & 1) * 65536;
    const float* hprev = (t == 0) ? h0 : (out + (long)(t - 1) * 1024);
    long hstride       = (t == 0) ? 1024 : (long)512 * 1024;
    step_kernel<<<dim3(128), dim3(256), 0, stream>>>(hA, hB, RT, P, whb, hprev,
                                                     hstride, out, t);
  }
}

// Round 2
// 7361.896 us; speedup vs baseline: 1.2564x; 1.2564x over previous
//
#include <hip/hip_runtime.h>
#include <hip/hip_bf16.h>

// GRU-variant: B=64, T=512, D=L=1024.
// Phase 1: P[b*T+t][3j+s] = x-part preactivations (triplet-permuted cols):
//   s=0: x@w_W[:, j] + w_b[j]; s=1: x@w_W[:, 1024+j] + w_b[1024+j]; s=2: x@wx_W[:, j] + wx_b[j]
// Phase 2: ONE persistent kernel, 512 steps. 4 independent batch-domains
// (16 batches) x 64 column-blocks (16 j = 48 permuted cols). Recurrent weights
// live in registers (B-frags preloaded once). Per-step sync: 64-block atomic
// arrive/spin per domain (release/acquire, agent scope). fp32 h in registers;
// bf16 h exchanged via double-buffered global.

typedef __attribute__((ext_vector_type(4))) int   int4v;
typedef __attribute__((ext_vector_type(4))) short short4v;
typedef __attribute__((ext_vector_type(8))) short bf16x8;
typedef __attribute__((ext_vector_type(4))) float f32x4;

union Pack16 { int4v i; short4v s[2]; };
union FragU  { bf16x8 v; short4v s[2]; };

__device__ __forceinline__ short f2bf(float f) {
  union { float f; unsigned u; } v; v.f = f;
  unsigned r = v.u + 0x7fffu + ((v.u >> 16) & 1u);   // round-to-nearest-even
  return (short)(r >> 16);
}
__device__ __forceinline__ float bf2f(short s) {
  union { unsigned u; float f; } v; v.u = ((unsigned)(unsigned short)s) << 16;
  return v.f;
}

// ---------------- prep kernels ----------------

__global__ __launch_bounds__(256) void cast_x_kernel(const float* __restrict__ xf,
                                                     short* __restrict__ xbf, int n4) {
  int i = blockIdx.x * 256 + threadIdx.x;
  if (i < n4) {
    float4 v = ((const float4*)xf)[i];
    short4v o;
    o.x = f2bf(v.x); o.y = f2bf(v.y); o.z = f2bf(v.z); o.w = f2bf(v.w);
    ((short4v*)xbf)[i] = o;
  }
}

// XwT: [3072][1024] bf16, row n=3j+s gathers column col(n) of the x-part weights.
// RT : [3104][1024] bf16 (rows 3072..3103 zero pad), h-part weights.
__global__ __launch_bounds__(256) void prep_weights(const float* __restrict__ wW,
                                                    const float* __restrict__ wxW,
                                                    const float* __restrict__ whW,
                                                    short* __restrict__ XwT,
                                                    short* __restrict__ RT) {
  int nb = blockIdx.x;
  if (nb < 3072) {
    int n = nb, j = n / 3, s = n % 3;
    for (int k = threadIdx.x; k < 1024; k += 256) {
      float v = (s == 0) ? wW[k * 2048 + j]
              : (s == 1) ? wW[k * 2048 + 1024 + j]
                         : wxW[k * 1024 + j];
      XwT[n * 1024 + k] = f2bf(v);
    }
  } else {
    int n = nb - 3072;  // 0..3103
    for (int k = threadIdx.x; k < 1024; k += 256) {
      float v = 0.f;
      if (n < 3072) {
        int j = n / 3, s = n % 3;
        v = (s == 0) ? wW[(1024 + k) * 2048 + j]
          : (s == 1) ? wW[(1024 + k) * 2048 + 1024 + j]
                     : whW[k * 1024 + j];
      }
      RT[n * 1024 + k] = f2bf(v);
    }
  }
}

// biasP (fp32, permuted) + h0 -> bf16 buffer 0
__global__ __launch_bounds__(256) void prep_misc(const float* __restrict__ wb,
                                                 const float* __restrict__ wxb,
                                                 const float* __restrict__ h0,
                                                 float* __restrict__ biasP,
                                                 short* __restrict__ hbf0) {
  int i = blockIdx.x * 256 + threadIdx.x;
  if (i < 65536) {
    hbf0[i] = f2bf(h0[i]);
  } else {
    int n = i - 65536;
    if (n < 3072) {
      int j = n / 3, s = n % 3;
      biasP[n] = (s == 0) ? wb[j] : (s == 1) ? wb[1024 + j] : wxb[j];
    }
  }
}

// ---------------- phase 1: P-GEMM ----------------
__global__ __launch_bounds__(256) void pgemm_kernel(const short* __restrict__ A,
                                                    const short* __restrict__ Bt,
                                                    const float* __restrict__ biasP,
                                                    short* __restrict__ P) {
  __shared__ short As[128][36];
  __shared__ short Bs[128][36];
  const int tid = threadIdx.x;
  const int m0 = blockIdx.y << 7;
  const int n0 = blockIdx.x << 7;
  const int w = tid >> 6, lane = tid & 63;
  const int wm = w >> 1, wn = w & 1;
  const int q = lane >> 4, r = lane & 15;
  const int srow = tid >> 1, shalf = tid & 1;

  const f32x4 zero = {0.f, 0.f, 0.f, 0.f};
  f32x4 acc[4][4];
#pragma unroll
  for (int a = 0; a < 4; ++a)
#pragma unroll
    for (int b = 0; b < 4; ++b) acc[a][b] = zero;

  const short* gA = A + (long)(m0 + srow) * 1024 + shalf * 16;
  const short* gB = Bt + (long)(n0 + srow) * 1024 + shalf * 16;

  for (int kk = 0; kk < 1024; kk += 32) {
    Pack16 a0, a1, b0, b1;
    a0.i = *(const int4v*)(gA + kk);
    a1.i = *(const int4v*)(gA + kk + 8);
    b0.i = *(const int4v*)(gB + kk);
    b1.i = *(const int4v*)(gB + kk + 8);
    short* wA = &As[srow][shalf * 16];
    *(short4v*)(wA)      = a0.s[0];
    *(short4v*)(wA + 4)  = a0.s[1];
    *(short4v*)(wA + 8)  = a1.s[0];
    *(short4v*)(wA + 12) = a1.s[1];
    short* wB = &Bs[srow][shalf * 16];
    *(short4v*)(wB)      = b0.s[0];
    *(short4v*)(wB + 4)  = b0.s[1];
    *(short4v*)(wB + 8)  = b1.s[0];
    *(short4v*)(wB + 12) = b1.s[1];
    __syncthreads();

    FragU af[4], bfv[4];
#pragma unroll
    for (int mi = 0; mi < 4; ++mi) {
      const short* pa = &As[wm * 64 + mi * 16 + r][q * 8];
      af[mi].s[0] = *(const short4v*)pa;
      af[mi].s[1] = *(const short4v*)(pa + 4);
    }
#pragma unroll
    for (int ni = 0; ni < 4; ++ni) {
      const short* pb = &Bs[wn * 64 + ni * 16 + r][q * 8];
      bfv[ni].s[0] = *(const short4v*)pb;
      bfv[ni].s[1] = *(const short4v*)(pb + 4);
    }
#pragma unroll
    for (int mi = 0; mi < 4; ++mi)
#pragma unroll
      for (int ni = 0; ni < 4; ++ni)
        acc[mi][ni] = __builtin_amdgcn_mfma_f32_16x16x32_bf16(af[mi].v, bfv[ni].v,
                                                              acc[mi][ni], 0, 0, 0);
    __syncthreads();
  }

#pragma unroll
  for (int ni = 0; ni < 4; ++ni) {
    int gn = n0 + wn * 64 + ni * 16 + r;        // C/D: col = lane&15
    float bias = biasP[gn];
#pragma unroll
    for (int mi = 0; mi < 4; ++mi) {
      int gm = m0 + wm * 64 + mi * 16 + q * 4;  // row = quad*4 + reg
#pragma unroll
      for (int i = 0; i < 4; ++i)
        P[(long)(gm + i) * 3072 + gn] = f2bf(acc[mi][ni][i] + bias);
    }
  }
}

// ---------------- phase 2: persistent recurrence ----------------
// Grid 256 = 4 batch-domains (bg) x 64 col-blocks (cg). Block: 256 thr (4 waves).
// Wave w owns K-slice [w*256, w*256+256). B-frags (RT) register-resident.
// Thread p=(bl,jl) owns h[bg*16+bl][cg*16+jl] fp32 in a register.
__global__ __launch_bounds__(256) void recur_kernel(const short* __restrict__ RT,
                                                    const short* __restrict__ P,
                                                    const float* __restrict__ whb,
                                                    const float* __restrict__ h0,
                                                    short* __restrict__ hbuf,
                                                    float* __restrict__ out,
                                                    unsigned* __restrict__ ctr) {
  __shared__ float Lred[4][3][256];
  const int tid = threadIdx.x;
  const int bid = blockIdx.x;
  const int cg = bid & 63, bg = bid >> 6;
  const int w = tid >> 6, lane = tid & 63;
  const int q = lane >> 4, r = lane & 15;
  const int ks = w << 8;
  const f32x4 zero = {0.f, 0.f, 0.f, 0.f};

  // Preload B-fragments for this wave's K-slice: 3 n-tiles x 8 k-iters.
  FragU Bf[3][8];
#pragma unroll
  for (int nt = 0; nt < 3; ++nt)
#pragma unroll
    for (int ki = 0; ki < 8; ++ki) {
      const short* p = RT + (long)(cg * 48 + nt * 16 + r) * 1024 + ks + ki * 32 + q * 8;
      Pack16 t16; t16.i = *(const int4v*)p;
      Bf[nt][ki].s[0] = t16.s[0]; Bf[nt][ki].s[1] = t16.s[1];
    }

  const int bl = tid >> 4, jl = tid & 15;
  float hp = h0[(long)(bg * 16 + bl) * 1024 + cg * 16 + jl];
  const float whbr = whb[cg * 16 + jl];
  const short* Pbase = P + ((long)(bg * 16 + bl) * 512) * 3072 + cg * 48 + jl * 3;
  short p0n = Pbase[0], p1n = Pbase[1], p2n = Pbase[2];   // step-0 prefetch
  unsigned* myctr = ctr + bg * 64;                        // 256B-separated counters
  const long outbase = ((long)(bg * 16 + bl) * 512) * 1024 + cg * 16 + jl;
  const int hidx = (bg * 16 + bl) * 1024 + cg * 16 + jl;

  for (int t = 0; t < 512; ++t) {
    const short* hcur = hbuf + (t & 1) * 65536;
    short* hnext = hbuf + ((t + 1) & 1) * 65536;

    // A-fragment loads for this step (bf16 h, from exchange buffer)
    FragU Af[8];
    const short* ap = hcur + (bg * 16 + r) * 1024 + ks + q * 8;
#pragma unroll
    for (int ki = 0; ki < 8; ++ki) {
      Pack16 t16; t16.i = *(const int4v*)(ap + ki * 32);
      Af[ki].s[0] = t16.s[0]; Af[ki].s[1] = t16.s[1];
    }

    // P prefetch for t+1 (lands during MFMA/epilogue)
    short c0 = p0n, c1 = p1n, c2 = p2n;
    if (t < 511) {
      const short* Pn = Pbase + (long)(t + 1) * 3072;
      p0n = Pn[0]; p1n = Pn[1]; p2n = Pn[2];
    }

    f32x4 acc0 = zero, acc1 = zero, acc2 = zero;
#pragma unroll
    for (int ki = 0; ki < 8; ++ki) {
      acc0 = __builtin_amdgcn_mfma_f32_16x16x32_bf16(Af[ki].v, Bf[0][ki].v, acc0, 0, 0, 0);
      acc1 = __builtin_amdgcn_mfma_f32_16x16x32_bf16(Af[ki].v, Bf[1][ki].v, acc1, 0, 0, 0);
      acc2 = __builtin_amdgcn_mfma_f32_16x16x32_bf16(Af[ki].v, Bf[2][ki].v, acc2, 0, 0, 0);
    }

    // cross-wave K reduction via LDS. C/D layout: col=r, row=q*4+i.
#pragma unroll
    for (int i = 0; i < 4; ++i) {
      Lred[w][0][(q * 4 + i) * 16 + r] = acc0[i];
      Lred[w][1][(q * 4 + i) * 16 + r] = acc1[i];
      Lred[w][2][(q * 4 + i) * 16 + r] = acc2[i];
    }
    __syncthreads();

    float g[3];
#pragma unroll
    for (int s = 0; s < 3; ++s) {
      int n = jl * 3 + s, nt = n >> 4, nc = n & 15;
      int idx = bl * 16 + nc;
      g[s] = Lred[0][nt][idx] + Lred[1][nt][idx] + Lred[2][nt][idx] + Lred[3][nt][idx];
    }
    float gh = 1.f / (1.f + __expf(-(bf2f(c0) + g[0])));
    float go = 1.f / (1.f + __expf(-(bf2f(c1) + g[1])));
    float mem = bf2f(c2) + gh * (g[2] + whbr);
    float e = __expf(2.f * mem);              // inf-safe tanh: 1 - 2/(e+1)
    float th = 1.f - 2.f / (e + 1.f);
    float hn = go * hp + (1.f - go) * th;
    hp = hn;
    out[outbase + (long)t * 1024] = hn;
    hnext[hidx] = f2bf(hn);

    __syncthreads();  // Lred reads done; all threads' stores issued+drained
    if (tid == 0) {
      __hip_atomic_fetch_add(myctr, 1u, __ATOMIC_RELEASE, __HIP_MEMORY_SCOPE_AGENT);
      unsigned tgt = 64u * (unsigned)(t + 1);
      while (__hip_atomic_load(myctr, __ATOMIC_ACQUIRE, __HIP_MEMORY_SCOPE_AGENT) < tgt)
        __builtin_amdgcn_s_sleep(1);
    }
    __syncthreads();
  }
}

// ---------------- launch ----------------

extern "C" void kernel_launch(void* const* d_in, const int* in_sizes, int n_in,
                              void* d_out, int out_size, void* d_ws, size_t ws_size,
                              hipStream_t stream) {
  const float* x   = (const float*)d_in[0];  // [64][512][1024]
  const float* h0  = (const float*)d_in[1];  // [64][1024]
  const float* wW  = (const float*)d_in[2];  // [2048][2048]
  const float* wb  = (const float*)d_in[3];  // [2048]
  const float* wxW = (const float*)d_in[4];  // [1024][1024]
  const float* wxb = (const float*)d_in[5];  // [1024]
  const float* whW = (const float*)d_in[6];  // [1024][1024]
  const float* whb = (const float*)d_in[7];  // [1024]
  float* out = (float*)d_out;                // [64][512][1024]

  char* ws = (char*)d_ws;
  short*    P     = (short*)(ws);               // 32768*3072*2 = 201326592
  short*    xbf   = (short*)(ws + 201326592);   // 67108864
  short*    XwT   = (short*)(ws + 268435456);   // 6291456
  short*    RT    = (short*)(ws + 274726912);   // 6356992
  float*    biasP = (float*)(ws + 281083904);   // 12288
  short*    hbf   = (short*)(ws + 281096192);   // 262144 (2 buffers)
  unsigned* ctr   = (unsigned*)(ws + 281358336);// 1024 (4 counters, 256B apart)

  hipMemsetAsync(ctr, 0, 1024, stream);
  cast_x_kernel<<<dim3(32768), dim3(256), 0, stream>>>(x, xbf, 8388608);
  prep_weights<<<dim3(6176), dim3(256), 0, stream>>>(wW, wxW, whW, XwT, RT);
  prep_misc<<<dim3(268), dim3(256), 0, stream>>>(wb, wxb, h0, biasP, hbf);
  pgemm_kernel<<<dim3(24, 256), dim3(256), 0, stream>>>(xbf, XwT, biasP, P);
  recur_kernel<<<dim3(256), dim3(256), 0, stream>>>(RT, P, whb, h0, hbf, out, ctr);
}

// Round 3
// 2678.006 us; speedup vs baseline: 3.4538x; 2.7490x over previous
//
#include <hip/hip_runtime.h>
#include <hip/hip_bf16.h>

// GRU-variant: B=64, T=512, D=L=1024.
// P layout: rows m = t*64+b, cols n: [0,1024)=gate_h x-part, [1024,2048)=gate_o
// x-part, [2048,3072)=qx. Recurrence: persistent kernel, fence-free sync:
// relaxed agent atomics + sc0sc1 write-through h exchange; fresh counter per
// step + go-flag; arrive-after-read makes double-buffered h race-free.

typedef __attribute__((ext_vector_type(4))) int   int4v;
typedef __attribute__((ext_vector_type(4))) short short4v;
typedef __attribute__((ext_vector_type(8))) short bf16x8;
typedef __attribute__((ext_vector_type(4))) float f32x4;

union Pack16 { int4v i; short4v s[2]; };
union FragU  { bf16x8 v; short4v s[2]; int4v i; };

__device__ __forceinline__ short f2bf(float f) {
  union { float f; unsigned u; } v; v.f = f;
  unsigned r = v.u + 0x7fffu + ((v.u >> 16) & 1u);
  return (short)(r >> 16);
}
__device__ __forceinline__ float bf2f(short s) {
  union { unsigned u; float f; } v; v.u = ((unsigned)(unsigned short)s) << 16;
  return v.f;
}

// ---------------- prep kernels ----------------

// x[b][t][k] -> xbf[(t*64+b)][k] (bf16)
__global__ __launch_bounds__(256) void cast_x_kernel(const float* __restrict__ xf,
                                                     short* __restrict__ xbf, int n4) {
  int i = blockIdx.x * 256 + threadIdx.x;
  if (i < n4) {
    float4 v = ((const float4*)xf)[i];
    short4v o;
    o.x = f2bf(v.x); o.y = f2bf(v.y); o.z = f2bf(v.z); o.w = f2bf(v.w);
    int r_in = i >> 8, c = i & 255;
    int b = r_in >> 9, t = r_in & 511;
    ((short4v*)xbf)[((t << 6) + b) * 256 + c] = o;
  }
}

// dst[n0+n][1024-k] = f2bf(src[k0+k][n0+n]); src ld given. 64x64 tiles.
__global__ __launch_bounds__(256) void transpose_cast(const float* __restrict__ src,
                                                      long ld, short* __restrict__ dst) {
  __shared__ float tile[64][65];
  const int n0 = blockIdx.x << 6, k0 = blockIdx.y << 6;
  const int c = threadIdx.x & 63, rr = threadIdx.x >> 6;
#pragma unroll 4
  for (int i = 0; i < 16; ++i)
    tile[i * 4 + rr][c] = src[(long)(k0 + i * 4 + rr) * ld + n0 + c];
  __syncthreads();
#pragma unroll 4
  for (int i = 0; i < 16; ++i)
    dst[(long)(n0 + i * 4 + rr) * 1024 + k0 + c] = f2bf(tile[c][i * 4 + rr]);
}

// biasP = [wb | wxb]; h0 -> bf16 buffer 0
__global__ __launch_bounds__(256) void prep_misc(const float* __restrict__ wb,
                                                 const float* __restrict__ wxb,
                                                 const float* __restrict__ h0,
                                                 float* __restrict__ biasP,
                                                 short* __restrict__ hbf0) {
  int i = blockIdx.x * 256 + threadIdx.x;
  if (i < 65536) {
    hbf0[i] = f2bf(h0[i]);
  } else {
    int n = i - 65536;
    if (n < 3072) biasP[n] = (n < 2048) ? wb[n] : wxb[n - 2048];
  }
}

// ---------------- phase 1: P-GEMM ----------------
__global__ __launch_bounds__(256) void pgemm_kernel(const short* __restrict__ A,
                                                    const short* __restrict__ Bt,
                                                    const float* __restrict__ biasP,
                                                    short* __restrict__ P) {
  __shared__ short As[128][36];
  __shared__ short Bs[128][36];
  const int tid = threadIdx.x;
  const int m0 = blockIdx.y << 7;
  const int n0 = blockIdx.x << 7;
  const int w = tid >> 6, lane = tid & 63;
  const int wm = w >> 1, wn = w & 1;
  const int q = lane >> 4, r = lane & 15;
  const int srow = tid >> 1, shalf = tid & 1;

  const f32x4 zero = {0.f, 0.f, 0.f, 0.f};
  f32x4 acc[4][4];
#pragma unroll
  for (int a = 0; a < 4; ++a)
#pragma unroll
    for (int b = 0; b < 4; ++b) acc[a][b] = zero;

  const short* gA = A + (long)(m0 + srow) * 1024 + shalf * 16;
  const short* gB = Bt + (long)(n0 + srow) * 1024 + shalf * 16;

  for (int kk = 0; kk < 1024; kk += 32) {
    Pack16 a0, a1, b0, b1;
    a0.i = *(const int4v*)(gA + kk);
    a1.i = *(const int4v*)(gA + kk + 8);
    b0.i = *(const int4v*)(gB + kk);
    b1.i = *(const int4v*)(gB + kk + 8);
    short* wA = &As[srow][shalf * 16];
    *(short4v*)(wA)      = a0.s[0];
    *(short4v*)(wA + 4)  = a0.s[1];
    *(short4v*)(wA + 8)  = a1.s[0];
    *(short4v*)(wA + 12) = a1.s[1];
    short* wB = &Bs[srow][shalf * 16];
    *(short4v*)(wB)      = b0.s[0];
    *(short4v*)(wB + 4)  = b0.s[1];
    *(short4v*)(wB + 8)  = b1.s[0];
    *(short4v*)(wB + 12) = b1.s[1];
    __syncthreads();

    FragU af[4], bfv[4];
#pragma unroll
    for (int mi = 0; mi < 4; ++mi) {
      const short* pa = &As[wm * 64 + mi * 16 + r][q * 8];
      af[mi].s[0] = *(const short4v*)pa;
      af[mi].s[1] = *(const short4v*)(pa + 4);
    }
#pragma unroll
    for (int ni = 0; ni < 4; ++ni) {
      const short* pb = &Bs[wn * 64 + ni * 16 + r][q * 8];
      bfv[ni].s[0] = *(const short4v*)pb;
      bfv[ni].s[1] = *(const short4v*)(pb + 4);
    }
#pragma unroll
    for (int mi = 0; mi < 4; ++mi)
#pragma unroll
      for (int ni = 0; ni < 4; ++ni)
        acc[mi][ni] = __builtin_amdgcn_mfma_f32_16x16x32_bf16(af[mi].v, bfv[ni].v,
                                                              acc[mi][ni], 0, 0, 0);
    __syncthreads();
  }

#pragma unroll
  for (int ni = 0; ni < 4; ++ni) {
    int gn = n0 + wn * 64 + ni * 16 + r;
    float bias = biasP[gn];
#pragma unroll
    for (int mi = 0; mi < 4; ++mi) {
      int gm = m0 + wm * 64 + mi * 16 + q * 4;
#pragma unroll
      for (int i = 0; i < 4; ++i)
        P[(long)(gm + i) * 3072 + gn] = f2bf(acc[mi][ni][i] + bias);
    }
  }
}

// ---------------- phase 2: persistent recurrence ----------------
// Grid 256 = 4 domains (bg, 16 batches) x 64 col-blocks (cg, 16 j).
// Wave w owns K-slice [w*256, +256). RT B-frags register-resident.
// Sync: fence-free. h exchange via sc0sc1 (L3-coherent) ops only.
__global__ __launch_bounds__(256, 1) void recur_kernel(const short* __restrict__ RT,
                                                       const short* __restrict__ P,
                                                       const float* __restrict__ whb,
                                                       const float* __restrict__ h0,
                                                       short* __restrict__ hbuf,
                                                       float* __restrict__ out,
                                                       unsigned* __restrict__ sync) {
  __shared__ float Lred[4][3][256];
  __shared__ unsigned long long hstage_u[32];
  short* hstage = (short*)hstage_u;

  const int tid = threadIdx.x;
  const int bid = blockIdx.x;
  const int cg = bid & 63, bg = bid >> 6;
  const int w = tid >> 6, lane = tid & 63;
  const int q = lane >> 4, r = lane & 15;
  const int ks = w << 8;
  const f32x4 zero = {0.f, 0.f, 0.f, 0.f};

  // B-frags: 3 n-tiles (j, 1024+j, 2048+j) x 8 k-iters, register/AGPR resident.
  FragU Bf[3][8];
#pragma unroll
  for (int nt = 0; nt < 3; ++nt)
#pragma unroll
    for (int ki = 0; ki < 8; ++ki) {
      const short* p = RT + (long)(nt * 1024 + cg * 16 + r) * 1024 + ks + ki * 32 + q * 8;
      Pack16 t16; t16.i = *(const int4v*)p;
      Bf[nt][ki].s[0] = t16.s[0]; Bf[nt][ki].s[1] = t16.s[1];
    }

  const int bl = tid >> 4, jl = tid & 15;
  float hp = h0[(long)(bg * 16 + bl) * 1024 + cg * 16 + jl];
  const float whbr = whb[cg * 16 + jl];
  const short* Pbase = P + (long)(bg * 16 + bl) * 3072 + cg * 16 + jl;
  short p0n = Pbase[0], p1n = Pbase[1024], p2n = Pbase[2048];  // t=0 prefetch
  const long outbase = ((long)(bg * 16 + bl) * 512) * 1024 + cg * 16 + jl;
  unsigned* gf = sync + 65536 + bg * 32;  // go-flag, own 128B line

  for (int t = 0; t < 512; ++t) {
    const short* hcur = hbuf + (t & 1) * 65536;
    short* hnext = hbuf + ((t + 1) & 1) * 65536;

    // A-frags: 8 x 16B coherent loads (bypass L1/L2, read L3) + tied waitcnt.
    const short* aptr = hcur + (bg * 16 + r) * 1024 + ks + q * 8;
    FragU Af[8];
    asm volatile(
        "global_load_dwordx4 %0, %8, off sc0 sc1\n\t"
        "global_load_dwordx4 %1, %8, off offset:64 sc0 sc1\n\t"
        "global_load_dwordx4 %2, %8, off offset:128 sc0 sc1\n\t"
        "global_load_dwordx4 %3, %8, off offset:192 sc0 sc1\n\t"
        "global_load_dwordx4 %4, %8, off offset:256 sc0 sc1\n\t"
        "global_load_dwordx4 %5, %8, off offset:320 sc0 sc1\n\t"
        "global_load_dwordx4 %6, %8, off offset:384 sc0 sc1\n\t"
        "global_load_dwordx4 %7, %8, off offset:448 sc0 sc1\n\t"
        "s_waitcnt vmcnt(0)"
        : "=&v"(Af[0].i), "=&v"(Af[1].i), "=&v"(Af[2].i), "=&v"(Af[3].i),
          "=&v"(Af[4].i), "=&v"(Af[5].i), "=&v"(Af[6].i), "=&v"(Af[7].i)
        : "v"(aptr)
        : "memory");

    // capture this step's P, prefetch t+1 (plain cached loads, land in L2)
    short c0 = p0n, c1 = p1n, c2 = p2n;
    if (t < 511) {
      const short* Pn = Pbase + (long)(t + 1) * 196608;
      p0n = Pn[0]; p1n = Pn[1024]; p2n = Pn[2048];
    }

    f32x4 acc0 = zero, acc1 = zero, acc2 = zero;
#pragma unroll
    for (int ki = 0; ki < 8; ++ki) {
      acc0 = __builtin_amdgcn_mfma_f32_16x16x32_bf16(Af[ki].v, Bf[0][ki].v, acc0, 0, 0, 0);
      acc1 = __builtin_amdgcn_mfma_f32_16x16x32_bf16(Af[ki].v, Bf[1][ki].v, acc1, 0, 0, 0);
      acc2 = __builtin_amdgcn_mfma_f32_16x16x32_bf16(Af[ki].v, Bf[2][ki].v, acc2, 0, 0, 0);
    }

    // cross-wave K reduction. C/D layout: col=r, row=q*4+i.
#pragma unroll
    for (int i = 0; i < 4; ++i) {
      Lred[w][0][(q * 4 + i) * 16 + r] = acc0[i];
      Lred[w][1][(q * 4 + i) * 16 + r] = acc1[i];
      Lred[w][2][(q * 4 + i) * 16 + r] = acc2[i];
    }
    __syncthreads();

    float g0 = Lred[0][0][tid] + Lred[1][0][tid] + Lred[2][0][tid] + Lred[3][0][tid];
    float g1 = Lred[0][1][tid] + Lred[1][1][tid] + Lred[2][1][tid] + Lred[3][1][tid];
    float g2 = Lred[0][2][tid] + Lred[1][2][tid] + Lred[2][2][tid] + Lred[3][2][tid];

    float gh = 1.f / (1.f + __expf(-(bf2f(c0) + g0)));
    float go = 1.f / (1.f + __expf(-(bf2f(c1) + g1)));
    float mem = bf2f(c2) + gh * (g2 + whbr);
    float e = __expf(2.f * mem);
    float th = 1.f - 2.f / (e + 1.f);
    float hn = go * hp + (1.f - go) * th;
    hp = hn;
    out[outbase + (long)t * 1024] = hn;
    hstage[tid] = f2bf(hn);
    __syncthreads();  // hstage visible to wave 0 (also: all Lred reads done)

    if (tid < 64) {  // wave 0: write-through h to L3, drain, arrive
      int row = bg * 16 + (tid >> 2);
      unsigned long long* hp64 = (unsigned long long*)(hnext + row * 1024 + cg * 16 + (tid & 3) * 4);
      __hip_atomic_store(hp64, hstage_u[tid], __ATOMIC_RELAXED, __HIP_MEMORY_SCOPE_AGENT);
      asm volatile("s_waitcnt vmcnt(0)" ::: "memory");
      if (tid == 0) {
        unsigned* ctr = sync + ((unsigned)t * 4 + bg) * 32;  // fresh line per step
        unsigned old = __hip_atomic_fetch_add(ctr, 1u, __ATOMIC_RELAXED,
                                              __HIP_MEMORY_SCOPE_AGENT);
        if (old == 63u)
          __hip_atomic_store(gf, (unsigned)(t + 1), __ATOMIC_RELAXED,
                             __HIP_MEMORY_SCOPE_AGENT);
      }
    }
    // everyone polls the read-only go-flag (relaxed; no cache invalidates)
    while (__hip_atomic_load(gf, __ATOMIC_RELAXED, __HIP_MEMORY_SCOPE_AGENT) <
           (unsigned)(t + 1))
      __builtin_amdgcn_s_sleep(1);
  }
}

// ---------------- launch ----------------

extern "C" void kernel_launch(void* const* d_in, const int* in_sizes, int n_in,
                              void* d_out, int out_size, void* d_ws, size_t ws_size,
                              hipStream_t stream) {
  const float* x   = (const float*)d_in[0];  // [64][512][1024]
  const float* h0  = (const float*)d_in[1];  // [64][1024]
  const float* wW  = (const float*)d_in[2];  // [2048][2048]
  const float* wb  = (const float*)d_in[3];  // [2048]
  const float* wxW = (const float*)d_in[4];  // [1024][1024]
  const float* wxb = (const float*)d_in[5];  // [1024]
  const float* whW = (const float*)d_in[6];  // [1024][1024]
  const float* whb = (const float*)d_in[7];  // [1024]
  float* out = (float*)d_out;                // [64][512][1024]

  char* ws = (char*)d_ws;
  short*    P     = (short*)(ws);               // 201326592
  short*    xbf   = (short*)(ws + 201326592);   // 67108864
  short*    XwT   = (short*)(ws + 268435456);   // 6291456
  short*    RT    = (short*)(ws + 274726912);   // 6291456
  float*    biasP = (float*)(ws + 281018368);   // 12288
  short*    hbf   = (short*)(ws + 281030656);   // 262144 (2 buffers)
  unsigned* sync  = (unsigned*)(ws + 281292800);// 262656 (512x4 ctr lines + 4 flags)

  hipMemsetAsync(sync, 0, 262656, stream);
  cast_x_kernel<<<dim3(32768), dim3(256), 0, stream>>>(x, xbf, 8388608);
  transpose_cast<<<dim3(32, 16), dim3(256), 0, stream>>>(wW, 2048, XwT);
  transpose_cast<<<dim3(16, 16), dim3(256), 0, stream>>>(wxW, 1024, XwT + 2048 * 1024);
  transpose_cast<<<dim3(32, 16), dim3(256), 0, stream>>>(wW + 1024 * 2048, 2048, RT);
  transpose_cast<<<dim3(16, 16), dim3(256), 0, stream>>>(whW, 1024, RT + 2048 * 1024);
  prep_misc<<<dim3(268), dim3(256), 0, stream>>>(wb, wxb, h0, biasP, hbf);
  pgemm_kernel<<<dim3(24, 256), dim3(256), 0, stream>>>(xbf, XwT, biasP, P);
  recur_kernel<<<dim3(256), dim3(256), 0, stream>>>(RT, P, whb, h0, hbf, out, sync);
}